// Round 9
// baseline (824.458 us; speedup 1.0000x reference)
//
#include <hip/hip_runtime.h>
#include <hip/hip_bf16.h>

// PermutationGenerator: B=8192, N=64, D=128, LATENT=256, TEMP=0.1, 20 Sinkhorn iters.
// d_in (ALL f32): [0] padded [B][64][128], [1] set_size int32 [B], [2] maskB (UNUSED),
//       [3] gumbel [B][64][64], [4] W1 [128][256], [5] b1 [256],
//       [6] W2 [256][64], [7] b2 [64]
// d_out f32: [0:8192] set_size, then permuted [B][64][128].
//
// R9: kernel A pipelined over 4 batches/block (grid 2048):
//   - x_{i+1} loaded to REGS at top of iter i, staged to LDS after GEMM2_i frees
//     the arena (T14 split: issue-early / write-late; ~1500cy of hiding).
//   - gn_i issued at top of iter i, consumed at init_i (~1200cy of hiding; was a
//     fully exposed tail stall).
//   - k[0..3], b1/b2 fragments prefetched at entry.
//   Kernel B unchanged (x T14 under Sinkhorn already; ~150us, near BW floor).
// R8 result: A=295us with VALU 12%/MFMA 7%/HBM 7% => ~85% exposed-latency stalls.

typedef _Float16 h16;
typedef h16 h8 __attribute__((ext_vector_type(8)));
typedef h16 h4 __attribute__((ext_vector_type(4)));
typedef __fp16 fp16x2 __attribute__((ext_vector_type(2)));
typedef float v4f __attribute__((ext_vector_type(4)));

template<int CTRL>
__device__ __forceinline__ float dppf(float x) {
  return __int_as_float(__builtin_amdgcn_update_dpp(
      0, __float_as_int(x), CTRL, 0xF, 0xF, true));
}
__device__ __forceinline__ float red16_sum(float x) {
  x += dppf<0xB1>(x);
  x += dppf<0x4E>(x);
  x += dppf<0x124>(x);
  x += dppf<0x128>(x);
  return x;
}
__device__ __forceinline__ float red16_max(float x) {
  x = fmaxf(x, dppf<0xB1>(x));
  x = fmaxf(x, dppf<0x4E>(x));
  x = fmaxf(x, dppf<0x124>(x));
  x = fmaxf(x, dppf<0x128>(x));
  return x;
}
__device__ __forceinline__ float frcp(float x) { return __builtin_amdgcn_rcpf(x); }
__device__ __forceinline__ h8 cvt8(v4f a, v4f b) {
  union { h8 v; fp16x2 p[4]; } u;
  u.p[0] = __builtin_amdgcn_cvt_pkrtz(a[0], a[1]);
  u.p[1] = __builtin_amdgcn_cvt_pkrtz(a[2], a[3]);
  u.p[2] = __builtin_amdgcn_cvt_pkrtz(b[0], b[1]);
  u.p[3] = __builtin_amdgcn_cvt_pkrtz(b[2], b[3]);
  return u.v;
}

__global__ __launch_bounds__(256) void prep_w(const float* __restrict__ W1,
                                              const float* __restrict__ W2,
                                              h16* __restrict__ w1t,
                                              h16* __restrict__ w2t) {
  int t = blockIdx.x * 256 + threadIdx.x;
  if (t < 128 * 256) {               // W1 [128][256] -> w1t [256 lat][128 f]
    int kq = t >> 8, n = t & 255;
    w1t[n * 128 + kq] = (h16)W1[t];
  } else if (t < 128 * 256 + 256 * 64) {  // W2 [256][64] -> w2t [64 j][256 lat]
    int t2 = t - 128 * 256;
    int kq = t2 >> 6, n = t2 & 63;
    w2t[n * 256 + kq] = (h16)W2[t2];
  }
}

// Runs LAST on the stream.
__global__ __launch_bounds__(256) void write_ss(const int* __restrict__ ssz,
                                                float* __restrict__ outp) {
  int b = blockIdx.x * 256 + threadIdx.x;
  if (b < 8192) outp[b] = (float)ssz[b];
}

// ================= Kernel A: MLP + Sinkhorn-init, 4 batches/block ============
// LDS arena 33792: xh f16 [64][136] -> hh f16 [64][264] (overlay per batch)
template<bool WSF>
__global__ __launch_bounds__(256, 4) void mlp_init(
    const float* __restrict__ xf,
    const int* __restrict__ ssz,
    const float* __restrict__ gn,
    const float* __restrict__ b1,
    const float* __restrict__ b2,
    const h16* __restrict__ w1t,   // [256][128]
    const h16* __restrict__ w2t,   // [64][256]
    const float* __restrict__ W1f,
    const float* __restrict__ W2f,
    float* __restrict__ outp) {
  __shared__ __align__(16) char smem[33792];
  h16* xh = (h16*)smem;   // [64][136]
  h16* hh = (h16*)smem;   // [64][264]

  const int tid = threadIdx.x;
  const int w = tid >> 6, lane = tid & 63, g = lane >> 4, lc = lane & 15;
  const int sr = tid >> 2, sseg = tid & 3;
  const int b0 = blockIdx.x * 4;

  // batch-independent prefetch
  int k4[4];
#pragma unroll
  for (int i = 0; i < 4; ++i) k4[i] = ssz[b0 + i];
  float b1v[4], b2v[4];
#pragma unroll
  for (int n = 0; n < 4; ++n) b1v[n] = b1[w * 64 + n * 16 + lc];
#pragma unroll
  for (int n = 0; n < 4; ++n) b2v[n] = b2[n * 16 + lc];

  // prologue: load x_0 -> regs -> LDS
  v4f xn[8];
  {
    const float* src = xf + (size_t)b0 * 8192 + sr * 128 + sseg * 32;
#pragma unroll
    for (int v = 0; v < 8; ++v) xn[v] = *(const v4f*)(src + v * 4);
  }
#pragma unroll
  for (int v = 0; v < 4; ++v)
    *(h8*)&xh[sr * 136 + sseg * 32 + v * 8] = cvt8(xn[2 * v], xn[2 * v + 1]);
  __syncthreads();

#pragma unroll 1
  for (int it = 0; it < 4; ++it) {
    const int b = b0 + it;
    const int k = k4[it];

    // issue x_{i+1} loads (consumed at end of this iter; hidden under GEMMs)
    if (it < 3) {
      const float* src = xf + (size_t)(b + 1) * 8192 + sr * 128 + sseg * 32;
#pragma unroll
      for (int v = 0; v < 8; ++v) xn[v] = *(const v4f*)(src + v * 4);
    }
    // issue gn_i loads (consumed at init_i; hidden under GEMM1+GEMM2)
    float gnr[4][4];
    {
      const float* gnb = gn + (size_t)b * 4096;
#pragma unroll
      for (int i = 0; i < 4; ++i)
#pragma unroll
        for (int n = 0; n < 4; ++n)
          gnr[i][n] = gnb[(16 * w + 4 * g + i) * 64 + 16 * n + lc];
    }

    // GEMM1: h = relu(x@W1+b1); wave w -> cols [64w,64w+64)
    v4f acc1[4][4];
#pragma unroll
    for (int m = 0; m < 4; ++m)
#pragma unroll
      for (int n = 0; n < 4; ++n) acc1[m][n] = (v4f){0.f, 0.f, 0.f, 0.f};
#pragma unroll
    for (int kk = 0; kk < 4; ++kk) {
      h8 av[4], bv[4];
#pragma unroll
      for (int m = 0; m < 4; ++m)
        av[m] = *(h8*)&xh[(lc + 16 * m) * 136 + kk * 32 + 8 * g];
#pragma unroll
      for (int n = 0; n < 4; ++n) {
        if (WSF) {
          bv[n] = *(const h8*)&w1t[(w * 64 + n * 16 + lc) * 128 + kk * 32 + 8 * g];
        } else {
          h8 t;
#pragma unroll
          for (int e = 0; e < 8; ++e)
            t[e] = (h16)W1f[(kk * 32 + 8 * g + e) * 256 + (w * 64 + n * 16 + lc)];
          bv[n] = t;
        }
      }
#pragma unroll
      for (int m = 0; m < 4; ++m)
#pragma unroll
        for (int n = 0; n < 4; ++n)
          acc1[m][n] = __builtin_amdgcn_mfma_f32_16x16x32_f16(av[m], bv[n], acc1[m][n], 0, 0, 0);
    }
    __syncthreads();   // xh dead
#pragma unroll
    for (int m = 0; m < 4; ++m)
#pragma unroll
      for (int n = 0; n < 4; ++n)
#pragma unroll
        for (int q = 0; q < 4; ++q)
          hh[(16 * m + 4 * g + q) * 264 + w * 64 + 16 * n + lc] =
              (h16)fmaxf(acc1[m][n][q] + b1v[n], 0.0f);
    __syncthreads();

    // GEMM2: net rows [16w,16w+16); thread owns rows 16w+4g+i, cols 16n+lc
    v4f acc2[4];
#pragma unroll
    for (int n = 0; n < 4; ++n) acc2[n] = (v4f){0.f, 0.f, 0.f, 0.f};
#pragma unroll
    for (int kk = 0; kk < 8; ++kk) {
      h8 av = *(h8*)&hh[(16 * w + lc) * 264 + kk * 32 + 8 * g];
#pragma unroll
      for (int n = 0; n < 4; ++n) {
        h8 bv;
        if (WSF) {
          bv = *(const h8*)&w2t[(n * 16 + lc) * 256 + kk * 32 + 8 * g];
        } else {
          h8 t;
#pragma unroll
          for (int e = 0; e < 8; ++e)
            t[e] = (h16)W2f[(kk * 32 + 8 * g + e) * 64 + (n * 16 + lc)];
          bv = t;
        }
        acc2[n] = __builtin_amdgcn_mfma_f32_16x16x32_f16(av, bv, acc2[n], 0, 0, 0);
      }
    }

    // init: P0 = exp2((la - rowmax)*10*log2e), masked -> 0 (gn already in regs)
    float p[4][4];
#pragma unroll
    for (int i = 0; i < 4; ++i)
#pragma unroll
      for (int n = 0; n < 4; ++n) p[i][n] = 0.0f;
    if (16 * w < k) {
#pragma unroll
      for (int i = 0; i < 4; ++i) {
        const int row = 16 * w + 4 * g + i;
        float la[4];
#pragma unroll
        for (int n = 0; n < 4; ++n) {
          const int col = 16 * n + lc;
          const bool valid = (row < k) && (col < k);
          const float v = acc2[n][i] + b2v[n] + gnr[i][n];
          la[n] = valid ? v : -1e30f;
        }
        float m_ = fmaxf(fmaxf(la[0], la[1]), fmaxf(la[2], la[3]));
        m_ = red16_max(m_);
#pragma unroll
        for (int n = 0; n < 4; ++n)
          p[i][n] = (la[n] > -1e29f) ? exp2f((la[n] - m_) * 14.4269504089f) : 0.0f;
      }
    }

    // store P0 f32 fragment-order: thread tid -> 64B at P0[tid*16]
    float* P0 = outp + 8192 + (size_t)b * 8192;
#pragma unroll
    for (int i = 0; i < 4; ++i) {
      v4f o;
#pragma unroll
      for (int n = 0; n < 4; ++n) o[n] = p[i][n];
      *(v4f*)&P0[tid * 16 + i * 4] = o;
    }

    // stage x_{i+1}: wait for hh readers, then overwrite arena
    if (it < 3) {
      __syncthreads();   // hh dead
#pragma unroll
      for (int v = 0; v < 4; ++v)
        *(h8*)&xh[sr * 136 + sseg * 32 + v * 8] = cvt8(xn[2 * v], xn[2 * v + 1]);
      __syncthreads();
    }
  }
}

// ================= Kernel B: Sinkhorn + GEMM3 + store ========================
// LDS 34944: xth f16 [128][72] @0 | pth f16 [64][72] @18432 | outst f32 [64][128]
// (overlay @0 after GEMM3) | part f32 @32768 (2176B)
__global__ __launch_bounds__(256) void sink_out(
    const float* __restrict__ xf,
    const int* __restrict__ ssz,
    float* __restrict__ outp) {
  __shared__ __align__(16) char smem[34944];
  h16* xth = (h16*)smem;
  h16* pth = (h16*)(smem + 18432);
  float* outst = (float*)smem;
  float* part = (float*)(smem + 32768);

  const int tid = threadIdx.x, b = blockIdx.x;
  const int w = tid >> 6, lane = tid & 63, g = lane >> 4, lc = lane & 15;
  const int sr = tid >> 2, sseg = tid & 3;

  // T14: issue x loads NOW, consume after Sinkhorn (latency hidden)
  v4f xr[8];
  {
    const float* src = xf + (size_t)b * 8192 + sr * 128 + sseg * 32;
#pragma unroll
    for (int v = 0; v < 8; ++v) xr[v] = *(const v4f*)(src + v * 4);
  }

  // load P0 f32 (same fragment mapping as kernel A)
  float p[4][4];
  {
    const float* P0 = outp + 8192 + (size_t)b * 8192;
#pragma unroll
    for (int i = 0; i < 4; ++i) {
      v4f t = *(const v4f*)&P0[tid * 16 + i * 4];
#pragma unroll
      for (int n = 0; n < 4; ++n) p[i][n] = t[n];
    }
  }

  // 20 iterations: row-normalize then col-normalize (exp domain)
#pragma unroll 1
  for (int it = 0; it < 20; ++it) {
#pragma unroll
    for (int i = 0; i < 4; ++i) {  // row norm: DPP-only
      float s = (p[i][0] + p[i][1]) + (p[i][2] + p[i][3]);
      s = red16_sum(s);
      const float sc = frcp(s + 1e-30f);
#pragma unroll
      for (int n = 0; n < 4; ++n) p[i][n] *= sc;
    }
    float cp[4];
#pragma unroll
    for (int n = 0; n < 4; ++n) {  // col partials over this wave's 16 rows
      float c = (p[0][n] + p[1][n]) + (p[2][n] + p[3][n]);
      c += __shfl_xor(c, 16);
      c += __shfl_xor(c, 32);
      cp[n] = c;
    }
    if (lane < 16) {
#pragma unroll
      for (int n = 0; n < 4; ++n)
        part[((it & 1) * 4 + w) * 68 + 16 * n + lc] = cp[n];
    }
    __syncthreads();
#pragma unroll
    for (int n = 0; n < 4; ++n) {
      float cs = 0.0f;
#pragma unroll
      for (int pw = 0; pw < 4; ++pw)
        cs += part[((it & 1) * 4 + pw) * 68 + 16 * n + lc];
      const float sc = frcp(cs + 1e-30f);
#pragma unroll
      for (int i = 0; i < 4; ++i) p[i][n] *= sc;
    }
  }

  // stage P^T and x^T
#pragma unroll
  for (int n = 0; n < 4; ++n) {
    h4 t;
#pragma unroll
    for (int i = 0; i < 4; ++i) t[i] = (h16)p[i][n];
    *(h4*)&pth[(16 * n + lc) * 72 + 16 * w + 4 * g] = t;  // P^T[col j][rows i..]
  }
#pragma unroll
  for (int v = 0; v < 4; ++v)
#pragma unroll
    for (int e = 0; e < 8; ++e) {
      const float xv = (e < 4) ? xr[2 * v][e] : xr[2 * v + 1][e - 4];
      xth[(sseg * 32 + v * 8 + e) * 72 + sr] = (h16)xv;  // x^T[f][i]
    }
  __syncthreads();

  // GEMM3 (full K=64): out = P^T @ x; wave w -> out cols [32w,32w+32)
  v4f acc3[4][2];
#pragma unroll
  for (int m = 0; m < 4; ++m)
#pragma unroll
    for (int nn = 0; nn < 2; ++nn) acc3[m][nn] = (v4f){0.f, 0.f, 0.f, 0.f};
#pragma unroll
  for (int kk = 0; kk < 2; ++kk) {
    h8 av[4], bv[2];
#pragma unroll
    for (int m = 0; m < 4; ++m)
      av[m] = *(h8*)&pth[(lc + 16 * m) * 72 + kk * 32 + 8 * g];
#pragma unroll
    for (int nn = 0; nn < 2; ++nn)
      bv[nn] = *(h8*)&xth[(32 * w + 16 * nn + lc) * 72 + kk * 32 + 8 * g];
#pragma unroll
    for (int m = 0; m < 4; ++m)
#pragma unroll
      for (int nn = 0; nn < 2; ++nn)
        acc3[m][nn] = __builtin_amdgcn_mfma_f32_16x16x32_f16(av[m], bv[nn], acc3[m][nn], 0, 0, 0);
  }
  __syncthreads();  // GEMM3 LDS reads done before outst overlays xth/pth

  // stage output skewed: outst[row][(col + 4*row) & 127]
#pragma unroll
  for (int m = 0; m < 4; ++m)
#pragma unroll
    for (int nn = 0; nn < 2; ++nn)
#pragma unroll
      for (int q = 0; q < 4; ++q) {
        const int row = 16 * m + 4 * g + q;
        const int col = 32 * w + 16 * nn + lc;
        outst[row * 128 + ((col + 4 * row) & 127)] = acc3[m][nn][q];
      }
  __syncthreads();

  {  // coalesced f32 store: 128B/thread (overwrites P0 region with final data)
    float* dst = outp + 8192 + (size_t)b * 8192 + sr * 128 + sseg * 32;
#pragma unroll
    for (int v = 0; v < 8; ++v) {
      const int coff = (sseg * 32 + v * 4 + 4 * sr) & 127;
      *(v4f*)(dst + v * 4) = *(v4f*)&outst[sr * 128 + coff];
    }
  }
}

extern "C" void kernel_launch(void* const* d_in, const int* in_sizes, int n_in,
                              void* d_out, int out_size, void* d_ws, size_t ws_size,
                              hipStream_t stream) {
  const float* xf = (const float*)d_in[0];
  const int* ssz = (const int*)d_in[1];
  // d_in[2] = maskB: unused (recomputed from set_size)
  const float* gn = (const float*)d_in[3];
  const float* W1 = (const float*)d_in[4];
  const float* b1 = (const float*)d_in[5];
  const float* W2 = (const float*)d_in[6];
  const float* b2 = (const float*)d_in[7];
  float* outp = (float*)d_out;

  const size_t ws_need = (size_t)(128 * 256 + 256 * 64) * sizeof(h16);  // 98304 B
  const bool use_ws = (d_ws != nullptr) && (ws_size >= ws_need);

  if (use_ws) {
    h16* w1t = (h16*)d_ws;             // [256][128] f16
    h16* w2t = w1t + 128 * 256;        // [64][256]  f16
    prep_w<<<192, 256, 0, stream>>>(W1, W2, w1t, w2t);
    mlp_init<true><<<2048, 256, 0, stream>>>(xf, ssz, gn, b1, b2, w1t, w2t,
                                             W1, W2, outp);
  } else {
    mlp_init<false><<<2048, 256, 0, stream>>>(xf, ssz, gn, b1, b2,
                                              (const h16*)nullptr,
                                              (const h16*)nullptr,
                                              W1, W2, outp);
  }
  sink_out<<<8192, 256, 0, stream>>>(xf, ssz, outp);
  // set_size written LAST so nothing can clobber [0:8192).
  write_ss<<<32, 256, 0, stream>>>(ssz, outp);
}

// Round 10
// 491.158 us; speedup vs baseline: 1.6786x; 1.6786x over previous
//
#include <hip/hip_runtime.h>
#include <hip/hip_bf16.h>

// PermutationGenerator: B=8192, N=64, D=128, LATENT=256, TEMP=0.1, 20 Sinkhorn iters.
// d_in (ALL f32): [0] padded [B][64][128], [1] set_size int32 [B], [2] maskB (UNUSED),
//       [3] gumbel [B][64][64], [4] W1 [128][256], [5] b1 [256],
//       [6] W2 [256][64], [7] b2 [64]
// d_out f32: [0:8192] set_size, then permuted [B][64][128].
//
// R10 (post R9 spill disaster: reg-prefetch across MFMA acc region => 650MB of
// scratch spill, A 295->634us):
//  A: R8 structure, block-per-batch, PLUS
//     - XOR-swizzled LDS (byte ^= (row&7)<<4): xh [64][128]=16KB, hh [64][256]=32KB,
//       arena 32768 => exactly 5 blocks/CU (was 4-ish at 33792). launch_bounds(256,5).
//     - gn prefetched in the LOW-pressure window (after GEMM1 MFMAs, lives only
//       across GEMM2; acc1 is dead by then) -> kills the exposed gn tail stall.
//     - P0 stored at P0[i*1024 + tid*4] (perfect 16B/lane coalescing).
//  B: unchanged except (a) P0 loads issued BEFORE x loads (vmcnt oldest-first:
//     P0 wait leaves x in flight), (b) matching P0 layout.

typedef _Float16 h16;
typedef h16 h8 __attribute__((ext_vector_type(8)));
typedef h16 h4 __attribute__((ext_vector_type(4)));
typedef __fp16 fp16x2 __attribute__((ext_vector_type(2)));
typedef float v4f __attribute__((ext_vector_type(4)));

template<int CTRL>
__device__ __forceinline__ float dppf(float x) {
  return __int_as_float(__builtin_amdgcn_update_dpp(
      0, __float_as_int(x), CTRL, 0xF, 0xF, true));
}
__device__ __forceinline__ float red16_sum(float x) {
  x += dppf<0xB1>(x);
  x += dppf<0x4E>(x);
  x += dppf<0x124>(x);
  x += dppf<0x128>(x);
  return x;
}
__device__ __forceinline__ float red16_max(float x) {
  x = fmaxf(x, dppf<0xB1>(x));
  x = fmaxf(x, dppf<0x4E>(x));
  x = fmaxf(x, dppf<0x124>(x));
  x = fmaxf(x, dppf<0x128>(x));
  return x;
}
__device__ __forceinline__ float frcp(float x) { return __builtin_amdgcn_rcpf(x); }
__device__ __forceinline__ h8 cvt8(v4f a, v4f b) {
  union { h8 v; fp16x2 p[4]; } u;
  u.p[0] = __builtin_amdgcn_cvt_pkrtz(a[0], a[1]);
  u.p[1] = __builtin_amdgcn_cvt_pkrtz(a[2], a[3]);
  u.p[2] = __builtin_amdgcn_cvt_pkrtz(b[0], b[1]);
  u.p[3] = __builtin_amdgcn_cvt_pkrtz(b[2], b[3]);
  return u.v;
}

__global__ __launch_bounds__(256) void prep_w(const float* __restrict__ W1,
                                              const float* __restrict__ W2,
                                              h16* __restrict__ w1t,
                                              h16* __restrict__ w2t) {
  int t = blockIdx.x * 256 + threadIdx.x;
  if (t < 128 * 256) {               // W1 [128][256] -> w1t [256 lat][128 f]
    int kq = t >> 8, n = t & 255;
    w1t[n * 128 + kq] = (h16)W1[t];
  } else if (t < 128 * 256 + 256 * 64) {  // W2 [256][64] -> w2t [64 j][256 lat]
    int t2 = t - 128 * 256;
    int kq = t2 >> 6, n = t2 & 63;
    w2t[n * 256 + kq] = (h16)W2[t2];
  }
}

// Runs LAST on the stream.
__global__ __launch_bounds__(256) void write_ss(const int* __restrict__ ssz,
                                                float* __restrict__ outp) {
  int b = blockIdx.x * 256 + threadIdx.x;
  if (b < 8192) outp[b] = (float)ssz[b];
}

// ================= Kernel A: MLP + Sinkhorn-init, store P0 (f32) =============
// LDS arena 32768 (5 blocks/CU): xh f16 [64][128] swz -> hh f16 [64][256] swz
template<bool WSF>
__global__ __launch_bounds__(256, 5) void mlp_init(
    const float* __restrict__ xf,
    const int* __restrict__ ssz,
    const float* __restrict__ gn,
    const float* __restrict__ b1,
    const float* __restrict__ b2,
    const h16* __restrict__ w1t,   // [256][128]
    const h16* __restrict__ w2t,   // [64][256]
    const float* __restrict__ W1f,
    const float* __restrict__ W2f,
    float* __restrict__ outp) {
  __shared__ __align__(16) char smem[32768];

  const int tid = threadIdx.x, b = blockIdx.x;
  const int w = tid >> 6, lane = tid & 63, g = lane >> 4, lc = lane & 15;
  const int k = ssz[b];
  const int sr = tid >> 2, sseg = tid & 3;

  {  // stage x -> f16 LDS xh [64][128] swizzled: byte = r*256 + c*2 ^ ((r&7)<<4)
    const float* src = xf + (size_t)b * 8192 + sr * 128 + sseg * 32;
#pragma unroll
    for (int v = 0; v < 4; ++v) {
      const int byte = (sr * 256 + (sseg * 32 + v * 8) * 2) ^ ((sr & 7) << 4);
      *(h8*)(smem + byte) =
          cvt8(*(const v4f*)(src + v * 8), *(const v4f*)(src + v * 8 + 4));
    }
  }
  float b1v[4], b2v[4];
#pragma unroll
  for (int n = 0; n < 4; ++n) b1v[n] = b1[w * 64 + n * 16 + lc];
#pragma unroll
  for (int n = 0; n < 4; ++n) b2v[n] = b2[n * 16 + lc];
  __syncthreads();

  // GEMM1: h = relu(x@W1+b1); wave w -> cols [64w,64w+64)
  v4f acc1[4][4];
#pragma unroll
  for (int m = 0; m < 4; ++m)
#pragma unroll
    for (int n = 0; n < 4; ++n) acc1[m][n] = (v4f){0.f, 0.f, 0.f, 0.f};
#pragma unroll
  for (int kk = 0; kk < 4; ++kk) {
    h8 av[4], bv[4];
#pragma unroll
    for (int m = 0; m < 4; ++m) {
      const int row = lc + 16 * m;
      const int byte = (row * 256 + (kk * 32 + 8 * g) * 2) ^ ((row & 7) << 4);
      av[m] = *(const h8*)(smem + byte);
    }
#pragma unroll
    for (int n = 0; n < 4; ++n) {
      if (WSF) {
        bv[n] = *(const h8*)&w1t[(w * 64 + n * 16 + lc) * 128 + kk * 32 + 8 * g];
      } else {
        h8 t;
#pragma unroll
        for (int e = 0; e < 8; ++e)
          t[e] = (h16)W1f[(kk * 32 + 8 * g + e) * 256 + (w * 64 + n * 16 + lc)];
        bv[n] = t;
      }
    }
#pragma unroll
    for (int m = 0; m < 4; ++m)
#pragma unroll
      for (int n = 0; n < 4; ++n)
        acc1[m][n] = __builtin_amdgcn_mfma_f32_16x16x32_f16(av[m], bv[n], acc1[m][n], 0, 0, 0);
  }

  // gn prefetch in LOW-pressure window (acc1 consumed right below; gnr lives
  // only across GEMM2) — removes the exposed gn tail stall.
  float gnr[4][4];
  {
    const float* gnb = gn + (size_t)b * 4096;
#pragma unroll
    for (int i = 0; i < 4; ++i)
#pragma unroll
      for (int n = 0; n < 4; ++n)
        gnr[i][n] = gnb[(16 * w + 4 * g + i) * 64 + 16 * n + lc];
  }

  __syncthreads();   // xh dead; arena becomes hh
  // hh store: byte = row*512 + col*2 ^ ((row&7)<<4)
#pragma unroll
  for (int m = 0; m < 4; ++m)
#pragma unroll
    for (int n = 0; n < 4; ++n)
#pragma unroll
      for (int q = 0; q < 4; ++q) {
        const int row = 16 * m + 4 * g + q;
        const int col = w * 64 + 16 * n + lc;
        const int byte = (row * 512 + col * 2) ^ ((row & 7) << 4);
        *(h16*)(smem + byte) = (h16)fmaxf(acc1[m][n][q] + b1v[n], 0.0f);
      }
  __syncthreads();

  // GEMM2: net rows [16w,16w+16); thread owns rows 16w+4g+i, cols 16n+lc
  v4f acc2[4];
#pragma unroll
  for (int n = 0; n < 4; ++n) acc2[n] = (v4f){0.f, 0.f, 0.f, 0.f};
  {
    const int row2 = 16 * w + lc;
#pragma unroll
    for (int kk = 0; kk < 8; ++kk) {
      const int byte = (row2 * 512 + (kk * 32 + 8 * g) * 2) ^ ((row2 & 7) << 4);
      h8 av = *(const h8*)(smem + byte);
#pragma unroll
      for (int n = 0; n < 4; ++n) {
        h8 bv;
        if (WSF) {
          bv = *(const h8*)&w2t[(n * 16 + lc) * 256 + kk * 32 + 8 * g];
        } else {
          h8 t;
#pragma unroll
          for (int e = 0; e < 8; ++e)
            t[e] = (h16)W2f[(kk * 32 + 8 * g + e) * 64 + (n * 16 + lc)];
          bv = t;
        }
        acc2[n] = __builtin_amdgcn_mfma_f32_16x16x32_f16(av, bv, acc2[n], 0, 0, 0);
      }
    }
  }

  // init: P0 = exp2((la - rowmax)*10*log2e), masked -> 0 (gn already in regs)
  float p[4][4];
#pragma unroll
  for (int i = 0; i < 4; ++i)
#pragma unroll
    for (int n = 0; n < 4; ++n) p[i][n] = 0.0f;
  if (16 * w < k) {
#pragma unroll
    for (int i = 0; i < 4; ++i) {
      const int row = 16 * w + 4 * g + i;
      float la[4];
#pragma unroll
      for (int n = 0; n < 4; ++n) {
        const int col = 16 * n + lc;
        const bool valid = (row < k) && (col < k);
        const float v = acc2[n][i] + b2v[n] + gnr[i][n];
        la[n] = valid ? v : -1e30f;
      }
      float m_ = fmaxf(fmaxf(la[0], la[1]), fmaxf(la[2], la[3]));
      m_ = red16_max(m_);
#pragma unroll
      for (int n = 0; n < 4; ++n)
        p[i][n] = (la[n] > -1e29f) ? exp2f((la[n] - m_) * 14.4269504089f) : 0.0f;
    }
  }

  // store P0 f32, fully coalesced: P0[i*1024 + tid*4]
  float* P0 = outp + 8192 + (size_t)b * 8192;
#pragma unroll
  for (int i = 0; i < 4; ++i) {
    v4f o;
#pragma unroll
    for (int n = 0; n < 4; ++n) o[n] = p[i][n];
    *(v4f*)&P0[i * 1024 + tid * 4] = o;
  }
}

// ================= Kernel B: Sinkhorn + GEMM3 + store ========================
// LDS 34944: xth f16 [128][72] @0 | pth f16 [64][72] @18432 | outst f32 [64][128]
// (overlay @0 after GEMM3) | part f32 @32768 (2176B)
__global__ __launch_bounds__(256) void sink_out(
    const float* __restrict__ xf,
    const int* __restrict__ ssz,
    float* __restrict__ outp) {
  __shared__ __align__(16) char smem[34944];
  h16* xth = (h16*)smem;
  h16* pth = (h16*)(smem + 18432);
  float* outst = (float*)smem;
  float* part = (float*)(smem + 32768);

  const int tid = threadIdx.x, b = blockIdx.x;
  const int w = tid >> 6, lane = tid & 63, g = lane >> 4, lc = lane & 15;
  const int sr = tid >> 2, sseg = tid & 3;

  // P0 loads FIRST (oldest in vmcnt queue: their wait leaves x in flight) ...
  v4f pr[4];
  {
    const float* P0 = outp + 8192 + (size_t)b * 8192;
#pragma unroll
    for (int i = 0; i < 4; ++i) pr[i] = *(const v4f*)&P0[i * 1024 + tid * 4];
  }
  // ... then x loads (T14: consumed after Sinkhorn, latency hidden)
  v4f xr[8];
  {
    const float* src = xf + (size_t)b * 8192 + sr * 128 + sseg * 32;
#pragma unroll
    for (int v = 0; v < 8; ++v) xr[v] = *(const v4f*)(src + v * 4);
  }

  float p[4][4];
#pragma unroll
  for (int i = 0; i < 4; ++i)
#pragma unroll
    for (int n = 0; n < 4; ++n) p[i][n] = pr[i][n];

  // 20 iterations: row-normalize then col-normalize (exp domain)
#pragma unroll 1
  for (int it = 0; it < 20; ++it) {
#pragma unroll
    for (int i = 0; i < 4; ++i) {  // row norm: DPP-only
      float s = (p[i][0] + p[i][1]) + (p[i][2] + p[i][3]);
      s = red16_sum(s);
      const float sc = frcp(s + 1e-30f);
#pragma unroll
      for (int n = 0; n < 4; ++n) p[i][n] *= sc;
    }
    float cp[4];
#pragma unroll
    for (int n = 0; n < 4; ++n) {  // col partials over this wave's 16 rows
      float c = (p[0][n] + p[1][n]) + (p[2][n] + p[3][n]);
      c += __shfl_xor(c, 16);
      c += __shfl_xor(c, 32);
      cp[n] = c;
    }
    if (lane < 16) {
#pragma unroll
      for (int n = 0; n < 4; ++n)
        part[((it & 1) * 4 + w) * 68 + 16 * n + lc] = cp[n];
    }
    __syncthreads();
#pragma unroll
    for (int n = 0; n < 4; ++n) {
      float cs = 0.0f;
#pragma unroll
      for (int pw = 0; pw < 4; ++pw)
        cs += part[((it & 1) * 4 + pw) * 68 + 16 * n + lc];
      const float sc = frcp(cs + 1e-30f);
#pragma unroll
      for (int i = 0; i < 4; ++i) p[i][n] *= sc;
    }
  }

  // stage P^T and x^T
#pragma unroll
  for (int n = 0; n < 4; ++n) {
    h4 t;
#pragma unroll
    for (int i = 0; i < 4; ++i) t[i] = (h16)p[i][n];
    *(h4*)&pth[(16 * n + lc) * 72 + 16 * w + 4 * g] = t;  // P^T[col j][rows i..]
  }
#pragma unroll
  for (int v = 0; v < 4; ++v)
#pragma unroll
    for (int e = 0; e < 8; ++e) {
      const float xv = (e < 4) ? xr[2 * v][e] : xr[2 * v + 1][e - 4];
      xth[(sseg * 32 + v * 8 + e) * 72 + sr] = (h16)xv;  // x^T[f][i]
    }
  __syncthreads();

  // GEMM3 (full K=64): out = P^T @ x; wave w -> out cols [32w,32w+32)
  v4f acc3[4][2];
#pragma unroll
  for (int m = 0; m < 4; ++m)
#pragma unroll
    for (int nn = 0; nn < 2; ++nn) acc3[m][nn] = (v4f){0.f, 0.f, 0.f, 0.f};
#pragma unroll
  for (int kk = 0; kk < 2; ++kk) {
    h8 av[4], bv[2];
#pragma unroll
    for (int m = 0; m < 4; ++m)
      av[m] = *(h8*)&pth[(lc + 16 * m) * 72 + kk * 32 + 8 * g];
#pragma unroll
    for (int nn = 0; nn < 2; ++nn)
      bv[nn] = *(h8*)&xth[(32 * w + 16 * nn + lc) * 72 + kk * 32 + 8 * g];
#pragma unroll
    for (int m = 0; m < 4; ++m)
#pragma unroll
      for (int nn = 0; nn < 2; ++nn)
        acc3[m][nn] = __builtin_amdgcn_mfma_f32_16x16x32_f16(av[m], bv[nn], acc3[m][nn], 0, 0, 0);
  }
  __syncthreads();  // GEMM3 LDS reads done before outst overlays xth/pth

  // stage output skewed: outst[row][(col + 4*row) & 127]
#pragma unroll
  for (int m = 0; m < 4; ++m)
#pragma unroll
    for (int nn = 0; nn < 2; ++nn)
#pragma unroll
      for (int q = 0; q < 4; ++q) {
        const int row = 16 * m + 4 * g + q;
        const int col = 32 * w + 16 * nn + lc;
        outst[row * 128 + ((col + 4 * row) & 127)] = acc3[m][nn][q];
      }
  __syncthreads();

  {  // coalesced f32 store: 128B/thread (overwrites P0 region with final data)
    float* dst = outp + 8192 + (size_t)b * 8192 + sr * 128 + sseg * 32;
#pragma unroll
    for (int v = 0; v < 8; ++v) {
      const int coff = (sseg * 32 + v * 4 + 4 * sr) & 127;
      *(v4f*)(dst + v * 4) = *(v4f*)&outst[sr * 128 + coff];
    }
  }
}

extern "C" void kernel_launch(void* const* d_in, const int* in_sizes, int n_in,
                              void* d_out, int out_size, void* d_ws, size_t ws_size,
                              hipStream_t stream) {
  const float* xf = (const float*)d_in[0];
  const int* ssz = (const int*)d_in[1];
  // d_in[2] = maskB: unused (recomputed from set_size)
  const float* gn = (const float*)d_in[3];
  const float* W1 = (const float*)d_in[4];
  const float* b1 = (const float*)d_in[5];
  const float* W2 = (const float*)d_in[6];
  const float* b2 = (const float*)d_in[7];
  float* outp = (float*)d_out;

  const size_t ws_need = (size_t)(128 * 256 + 256 * 64) * sizeof(h16);  // 98304 B
  const bool use_ws = (d_ws != nullptr) && (ws_size >= ws_need);

  if (use_ws) {
    h16* w1t = (h16*)d_ws;             // [256][128] f16
    h16* w2t = w1t + 128 * 256;        // [64][256]  f16
    prep_w<<<192, 256, 0, stream>>>(W1, W2, w1t, w2t);
    mlp_init<true><<<8192, 256, 0, stream>>>(xf, ssz, gn, b1, b2, w1t, w2t,
                                             W1, W2, outp);
  } else {
    mlp_init<false><<<8192, 256, 0, stream>>>(xf, ssz, gn, b1, b2,
                                              (const h16*)nullptr,
                                              (const h16*)nullptr,
                                              W1, W2, outp);
  }
  sink_out<<<8192, 256, 0, stream>>>(xf, ssz, outp);
  // set_size written LAST so nothing can clobber [0:8192).
  write_ss<<<32, 256, 0, stream>>>(ssz, outp);
}

// Round 11
// 481.985 us; speedup vs baseline: 1.7105x; 1.0190x over previous
//
#include <hip/hip_runtime.h>
#include <hip/hip_bf16.h>

// PermutationGenerator: B=8192, N=64, D=128, LATENT=256, TEMP=0.1, 20 Sinkhorn iters.
// d_in (ALL f32): [0] padded [B][64][128], [1] set_size int32 [B], [2] maskB (UNUSED),
//       [3] gumbel [B][64][64], [4] W1 [128][256], [5] b1 [256],
//       [6] W2 [256][64], [7] b2 [64]
// d_out f32: [0:8192] set_size, then permuted [B][64][128].
//
// R11: kernel B -> WAVE-PER-BATCH, ZERO barriers (R5-verified pieces):
//   - A stores P0 scattered into B-wave fragment order; B loads it with 16
//     perfectly-coalesced v4f loads -> p[mj][nr][q] = P[16nr+lc][16mj+4g+q].
//   - 20 Sinkhorn iters fully in-register (row: in-lane + 2 shfl_xor; col:
//     in-lane + 4 DPP). Masked entries are exactly 0 and stay 0 (no masks).
//   - GEMM3 per wave: private 8KB subtiled pth (conflict-free b128), x loads
//     and stores scatter-but-line-full (4x64B lines/instr). All R5-verified.
//   A: unchanged except gn prefetch gated on wave-active (FETCH regression fix)
//      and the P0 store layout.

typedef _Float16 h16;
typedef h16 h8 __attribute__((ext_vector_type(8)));
typedef __fp16 fp16x2 __attribute__((ext_vector_type(2)));
typedef float v4f __attribute__((ext_vector_type(4)));

template<int CTRL>
__device__ __forceinline__ float dppf(float x) {
  return __int_as_float(__builtin_amdgcn_update_dpp(
      0, __float_as_int(x), CTRL, 0xF, 0xF, true));
}
__device__ __forceinline__ float red16_sum(float x) {
  x += dppf<0xB1>(x);
  x += dppf<0x4E>(x);
  x += dppf<0x124>(x);
  x += dppf<0x128>(x);
  return x;
}
__device__ __forceinline__ float red16_max(float x) {
  x = fmaxf(x, dppf<0xB1>(x));
  x = fmaxf(x, dppf<0x4E>(x));
  x = fmaxf(x, dppf<0x124>(x));
  x = fmaxf(x, dppf<0x128>(x));
  return x;
}
__device__ __forceinline__ float frcp(float x) { return __builtin_amdgcn_rcpf(x); }
__device__ __forceinline__ h8 cvt8(v4f a, v4f b) {
  union { h8 v; fp16x2 p[4]; } u;
  u.p[0] = __builtin_amdgcn_cvt_pkrtz(a[0], a[1]);
  u.p[1] = __builtin_amdgcn_cvt_pkrtz(a[2], a[3]);
  u.p[2] = __builtin_amdgcn_cvt_pkrtz(b[0], b[1]);
  u.p[3] = __builtin_amdgcn_cvt_pkrtz(b[2], b[3]);
  return u.v;
}

__global__ __launch_bounds__(256) void prep_w(const float* __restrict__ W1,
                                              const float* __restrict__ W2,
                                              h16* __restrict__ w1t,
                                              h16* __restrict__ w2t) {
  int t = blockIdx.x * 256 + threadIdx.x;
  if (t < 128 * 256) {               // W1 [128][256] -> w1t [256 lat][128 f]
    int kq = t >> 8, n = t & 255;
    w1t[n * 128 + kq] = (h16)W1[t];
  } else if (t < 128 * 256 + 256 * 64) {  // W2 [256][64] -> w2t [64 j][256 lat]
    int t2 = t - 128 * 256;
    int kq = t2 >> 6, n = t2 & 63;
    w2t[n * 256 + kq] = (h16)W2[t2];
  }
}

// Runs LAST on the stream.
__global__ __launch_bounds__(256) void write_ss(const int* __restrict__ ssz,
                                                float* __restrict__ outp) {
  int b = blockIdx.x * 256 + threadIdx.x;
  if (b < 8192) outp[b] = (float)ssz[b];
}

// ================= Kernel A: MLP + Sinkhorn-init, store P0 (f32) =============
// LDS arena 32768 (5 blocks/CU): xh f16 [64][128] swz -> hh f16 [64][256] swz
template<bool WSF>
__global__ __launch_bounds__(256, 5) void mlp_init(
    const float* __restrict__ xf,
    const int* __restrict__ ssz,
    const float* __restrict__ gn,
    const float* __restrict__ b1,
    const float* __restrict__ b2,
    const h16* __restrict__ w1t,   // [256][128]
    const h16* __restrict__ w2t,   // [64][256]
    const float* __restrict__ W1f,
    const float* __restrict__ W2f,
    float* __restrict__ outp) {
  __shared__ __align__(16) char smem[32768];

  const int tid = threadIdx.x, b = blockIdx.x;
  const int w = tid >> 6, lane = tid & 63, g = lane >> 4, lc = lane & 15;
  const int k = ssz[b];
  const int sr = tid >> 2, sseg = tid & 3;

  {  // stage x -> f16 LDS xh [64][128] swizzled: byte = r*256 + c*2 ^ ((r&7)<<4)
    const float* src = xf + (size_t)b * 8192 + sr * 128 + sseg * 32;
#pragma unroll
    for (int v = 0; v < 4; ++v) {
      const int byte = (sr * 256 + (sseg * 32 + v * 8) * 2) ^ ((sr & 7) << 4);
      *(h8*)(smem + byte) =
          cvt8(*(const v4f*)(src + v * 8), *(const v4f*)(src + v * 8 + 4));
    }
  }
  float b1v[4], b2v[4];
#pragma unroll
  for (int n = 0; n < 4; ++n) b1v[n] = b1[w * 64 + n * 16 + lc];
#pragma unroll
  for (int n = 0; n < 4; ++n) b2v[n] = b2[n * 16 + lc];
  __syncthreads();

  // GEMM1: h = relu(x@W1+b1); wave w -> cols [64w,64w+64)
  v4f acc1[4][4];
#pragma unroll
  for (int m = 0; m < 4; ++m)
#pragma unroll
    for (int n = 0; n < 4; ++n) acc1[m][n] = (v4f){0.f, 0.f, 0.f, 0.f};
#pragma unroll
  for (int kk = 0; kk < 4; ++kk) {
    h8 av[4], bv[4];
#pragma unroll
    for (int m = 0; m < 4; ++m) {
      const int row = lc + 16 * m;
      const int byte = (row * 256 + (kk * 32 + 8 * g) * 2) ^ ((row & 7) << 4);
      av[m] = *(const h8*)(smem + byte);
    }
#pragma unroll
    for (int n = 0; n < 4; ++n) {
      if (WSF) {
        bv[n] = *(const h8*)&w1t[(w * 64 + n * 16 + lc) * 128 + kk * 32 + 8 * g];
      } else {
        h8 t;
#pragma unroll
        for (int e = 0; e < 8; ++e)
          t[e] = (h16)W1f[(kk * 32 + 8 * g + e) * 256 + (w * 64 + n * 16 + lc)];
        bv[n] = t;
      }
    }
#pragma unroll
    for (int m = 0; m < 4; ++m)
#pragma unroll
      for (int n = 0; n < 4; ++n)
        acc1[m][n] = __builtin_amdgcn_mfma_f32_16x16x32_f16(av[m], bv[n], acc1[m][n], 0, 0, 0);
  }

  // gn prefetch in LOW-pressure window; gated on wave-active (FETCH fix)
  float gnr[4][4];
  if (16 * w < k) {
    const float* gnb = gn + (size_t)b * 4096;
#pragma unroll
    for (int i = 0; i < 4; ++i)
#pragma unroll
      for (int n = 0; n < 4; ++n)
        gnr[i][n] = gnb[(16 * w + 4 * g + i) * 64 + 16 * n + lc];
  }

  __syncthreads();   // xh dead; arena becomes hh
  // hh store: byte = row*512 + col*2 ^ ((row&7)<<4)
#pragma unroll
  for (int m = 0; m < 4; ++m)
#pragma unroll
    for (int n = 0; n < 4; ++n)
#pragma unroll
      for (int q = 0; q < 4; ++q) {
        const int row = 16 * m + 4 * g + q;
        const int col = w * 64 + 16 * n + lc;
        const int byte = (row * 512 + col * 2) ^ ((row & 7) << 4);
        *(h16*)(smem + byte) = (h16)fmaxf(acc1[m][n][q] + b1v[n], 0.0f);
      }
  __syncthreads();

  // GEMM2: net rows [16w,16w+16); thread owns rows 16w+4g+i, cols 16n+lc
  v4f acc2[4];
#pragma unroll
  for (int n = 0; n < 4; ++n) acc2[n] = (v4f){0.f, 0.f, 0.f, 0.f};
  {
    const int row2 = 16 * w + lc;
#pragma unroll
    for (int kk = 0; kk < 8; ++kk) {
      const int byte = (row2 * 512 + (kk * 32 + 8 * g) * 2) ^ ((row2 & 7) << 4);
      h8 av = *(const h8*)(smem + byte);
#pragma unroll
      for (int n = 0; n < 4; ++n) {
        h8 bv;
        if (WSF) {
          bv = *(const h8*)&w2t[(n * 16 + lc) * 256 + kk * 32 + 8 * g];
        } else {
          h8 t;
#pragma unroll
          for (int e = 0; e < 8; ++e)
            t[e] = (h16)W2f[(kk * 32 + 8 * g + e) * 64 + (n * 16 + lc)];
          bv = t;
        }
        acc2[n] = __builtin_amdgcn_mfma_f32_16x16x32_f16(av, bv, acc2[n], 0, 0, 0);
      }
    }
  }

  // init: P0 = exp2((la - rowmax)*10*log2e), masked -> 0 (gn already in regs)
  float p[4][4];
#pragma unroll
  for (int i = 0; i < 4; ++i)
#pragma unroll
    for (int n = 0; n < 4; ++n) p[i][n] = 0.0f;
  if (16 * w < k) {
#pragma unroll
    for (int i = 0; i < 4; ++i) {
      const int row = 16 * w + 4 * g + i;
      float la[4];
#pragma unroll
      for (int n = 0; n < 4; ++n) {
        const int col = 16 * n + lc;
        const bool valid = (row < k) && (col < k);
        const float v = acc2[n][i] + b2v[n] + gnr[i][n];
        la[n] = valid ? v : -1e30f;
      }
      float m_ = fmaxf(fmaxf(la[0], la[1]), fmaxf(la[2], la[3]));
      m_ = red16_max(m_);
#pragma unroll
      for (int n = 0; n < 4; ++n)
        p[i][n] = (la[n] > -1e29f) ? exp2f((la[n] - m_) * 14.4269504089f) : 0.0f;
    }
  }

  // store P0 f32 in B-WAVE fragment order:
  //   flat[((mj*4+nr)*64 + L)*4 + q] = P[16nr + (L&15)][16mj + 4*(L>>4) + q]
  // A thread (w,g,lc) element (i,n): nr=w, mj=n, L=16*(lc>>2)+4g+i, q=lc&3.
  float* P0 = outp + 8192 + (size_t)b * 8192;
#pragma unroll
  for (int i = 0; i < 4; ++i)
#pragma unroll
    for (int n = 0; n < 4; ++n)
      P0[(n * 256 + w * 64 + 16 * (lc >> 2) + 4 * g + i) * 4 + (lc & 3)] = p[i][n];
}

// ================= Kernel B: wave-per-batch Sinkhorn + GEMM3, ZERO barriers ==
// Per-wave private 8KB pth: P^T subtiled [i>>3][j][i&7] f16 (conflict-free b128)
__global__ __launch_bounds__(256, 4) void sink_out(
    const float* __restrict__ xf,
    const int* __restrict__ ssz,
    float* __restrict__ outp) {
  __shared__ h16 pth_all[4][4096];

  const int tid = threadIdx.x;
  const int w = tid >> 6, lane = tid & 63, g = lane >> 4, lc = lane & 15;
  h16* pth = pth_all[w];

  const int b = blockIdx.x * 4 + w;
  const int k = ssz[b];
  const int mcnt = (k + 15) >> 4;
  const int kk3max = (k + 31) >> 5;
  const float* xb = xf + (size_t)b * 8192;

  // load P0: 16 coalesced v4f -> p[mj][nr][q] = P[16nr+lc][16mj+4g+q]
  v4f p[4][4];
  {
    const float* P0 = outp + 8192 + (size_t)b * 8192;
#pragma unroll
    for (int mj = 0; mj < 4; ++mj)
#pragma unroll
      for (int nr = 0; nr < 4; ++nr)
        p[mj][nr] = *(const v4f*)&P0[((mj * 4 + nr) * 64 + lane) * 4];
  }

  // 20 Sinkhorn iterations, fully in-register, zero barriers
#pragma unroll 1
  for (int it = 0; it < 20; ++it) {
    // row-normalize (over j): in-lane (mj,q) + shfl_xor across 16-lane groups
#pragma unroll
    for (int nr = 0; nr < 4; ++nr)
      if (nr < mcnt) {
        float s = 0.0f;
#pragma unroll
        for (int mj = 0; mj < 4; ++mj)
          if (mj < mcnt)
            s += (p[mj][nr][0] + p[mj][nr][1]) + (p[mj][nr][2] + p[mj][nr][3]);
        s += __shfl_xor(s, 16);
        s += __shfl_xor(s, 32);
        const float sc = frcp(s + 1e-30f);
#pragma unroll
        for (int mj = 0; mj < 4; ++mj)
          if (mj < mcnt) {
            p[mj][nr][0] *= sc; p[mj][nr][1] *= sc;
            p[mj][nr][2] *= sc; p[mj][nr][3] *= sc;
          }
      }
    // col-normalize (over r): in-lane (nr) + DPP across 16 lanes
#pragma unroll
    for (int mj = 0; mj < 4; ++mj)
      if (mj < mcnt) {
#pragma unroll
        for (int q = 0; q < 4; ++q) {
          float c = 0.0f;
#pragma unroll
          for (int nr = 0; nr < 4; ++nr)
            if (nr < mcnt) c += p[mj][nr][q];
          c = red16_sum(c);
          const float sc = frcp(c + 1e-30f);
#pragma unroll
          for (int nr = 0; nr < 4; ++nr)
            if (nr < mcnt) p[mj][nr][q] *= sc;
        }
      }
  }

  // stage P^T: pth[(i>>3)*512 + j*8 + (i&7)], i = 16nr+lc, j = 16mj+4g+q
#pragma unroll
  for (int mj = 0; mj < 4; ++mj)
#pragma unroll
    for (int nr = 0; nr < 4; ++nr)
#pragma unroll
      for (int q = 0; q < 4; ++q)
        pth[((2 * nr + (lc >> 3)) * 64 + 16 * mj + 4 * g + q) * 8 + (lc & 7)] =
            (h16)p[mj][nr][q];
  asm volatile("s_waitcnt lgkmcnt(0)" ::: "memory");

  float* outb = outp + 8192 + (size_t)b * 8192;
#pragma unroll 1
  for (int c = 0; c < 4; ++c) {  // f-chunks of 32
    v4f acc3[4][2];
#pragma unroll
    for (int m = 0; m < 4; ++m)
#pragma unroll
      for (int nn = 0; nn < 2; ++nn) acc3[m][nn] = (v4f){0.f, 0.f, 0.f, 0.f};
#pragma unroll 1
    for (int kk = 0; kk < kk3max; ++kk) {
      h8 ap[4];
#pragma unroll
      for (int m = 0; m < 4; ++m)
        if (m < mcnt)
          ap[m] = *(const h8*)&pth[((4 * kk + g) * 64 + 16 * m + lc) * 8];
#pragma unroll
      for (int nn = 0; nn < 2; ++nn) {
        const int f = 16 * (2 * c + nn) + lc;
        v4f x0, x1;
#pragma unroll
        for (int e = 0; e < 4; ++e) x0[e] = xb[(kk * 32 + 8 * g + e) * 128 + f];
#pragma unroll
        for (int e = 0; e < 4; ++e) x1[e] = xb[(kk * 32 + 8 * g + 4 + e) * 128 + f];
        h8 bxx = cvt8(x0, x1);
#pragma unroll
        for (int m = 0; m < 4; ++m)
          if (m < mcnt)
            acc3[m][nn] = __builtin_amdgcn_mfma_f32_16x16x32_f16(ap[m], bxx, acc3[m][nn], 0, 0, 0);
      }
    }
    // stores: 4x64B full lines per instruction; rows j>=k store zeros
#pragma unroll
    for (int m = 0; m < 4; ++m)
#pragma unroll
      for (int nn = 0; nn < 2; ++nn)
#pragma unroll
        for (int q = 0; q < 4; ++q)
          outb[(16 * m + 4 * g + q) * 128 + 16 * (2 * c + nn) + lc] = acc3[m][nn][q];
  }
}

extern "C" void kernel_launch(void* const* d_in, const int* in_sizes, int n_in,
                              void* d_out, int out_size, void* d_ws, size_t ws_size,
                              hipStream_t stream) {
  const float* xf = (const float*)d_in[0];
  const int* ssz = (const int*)d_in[1];
  // d_in[2] = maskB: unused (recomputed from set_size)
  const float* gn = (const float*)d_in[3];
  const float* W1 = (const float*)d_in[4];
  const float* b1 = (const float*)d_in[5];
  const float* W2 = (const float*)d_in[6];
  const float* b2 = (const float*)d_in[7];
  float* outp = (float*)d_out;

  const size_t ws_need = (size_t)(128 * 256 + 256 * 64) * sizeof(h16);  // 98304 B
  const bool use_ws = (d_ws != nullptr) && (ws_size >= ws_need);

  if (use_ws) {
    h16* w1t = (h16*)d_ws;             // [256][128] f16
    h16* w2t = w1t + 128 * 256;        // [64][256]  f16
    prep_w<<<192, 256, 0, stream>>>(W1, W2, w1t, w2t);
    mlp_init<true><<<8192, 256, 0, stream>>>(xf, ssz, gn, b1, b2, w1t, w2t,
                                             W1, W2, outp);
  } else {
    mlp_init<false><<<8192, 256, 0, stream>>>(xf, ssz, gn, b1, b2,
                                              (const h16*)nullptr,
                                              (const h16*)nullptr,
                                              W1, W2, outp);
  }
  sink_out<<<2048, 256, 0, stream>>>(xf, ssz, outp);
  // set_size written LAST so nothing can clobber [0:8192).
  write_ss<<<32, 256, 0, stream>>>(ssz, outp);
}

// Round 12
// 444.502 us; speedup vs baseline: 1.8548x; 1.0843x over previous
//
#include <hip/hip_runtime.h>
#include <hip/hip_bf16.h>

// PermutationGenerator: B=8192, N=64, D=128, LATENT=256, TEMP=0.1, 20 Sinkhorn iters.
// d_in (ALL f32): [0] padded [B][64][128], [1] set_size int32 [B], [2] maskB (UNUSED),
//       [3] gumbel [B][64][64], [4] W1 [128][256], [5] b1 [256],
//       [6] W2 [256][64], [7] b2 [64]
// d_out f32: [0:8192] set_size, then permuted [B][64][128].
//
// R12 (A-only changes; B is ~5TB/s => at roofline, untouched):
//  1. COALESCED weight staging: w1s[kk][col][e], w2s[kk][j][e] (k-within-32
//     innermost). A wave's bv load now covers 16 FULLY-USED 64B lines/instr
//     (was 64 lines at 25% use) -> 4x less L2 traffic. Same MFMA fragments.
//  2. P0 store via LDS transpose (arena dead post-GEMM2): scatter to B-wave
//     flat order in LDS (+4dw/32 pad, 16B-aligned reads), then 64B-contiguous
//     per-thread global stores. Fixes R11's 452MB write inflation (partial
//     64B lines -> write-allocate RMW). R8-verified clean pattern.
//  B: R11 wave-per-batch zero-barrier Sinkhorn+GEMM3 (passed, absmax 0.03125).

typedef _Float16 h16;
typedef h16 h8 __attribute__((ext_vector_type(8)));
typedef __fp16 fp16x2 __attribute__((ext_vector_type(2)));
typedef float v4f __attribute__((ext_vector_type(4)));

template<int CTRL>
__device__ __forceinline__ float dppf(float x) {
  return __int_as_float(__builtin_amdgcn_update_dpp(
      0, __float_as_int(x), CTRL, 0xF, 0xF, true));
}
__device__ __forceinline__ float red16_sum(float x) {
  x += dppf<0xB1>(x);
  x += dppf<0x4E>(x);
  x += dppf<0x124>(x);
  x += dppf<0x128>(x);
  return x;
}
__device__ __forceinline__ float red16_max(float x) {
  x = fmaxf(x, dppf<0xB1>(x));
  x = fmaxf(x, dppf<0x4E>(x));
  x = fmaxf(x, dppf<0x124>(x));
  x = fmaxf(x, dppf<0x128>(x));
  return x;
}
__device__ __forceinline__ float frcp(float x) { return __builtin_amdgcn_rcpf(x); }
__device__ __forceinline__ h8 cvt8(v4f a, v4f b) {
  union { h8 v; fp16x2 p[4]; } u;
  u.p[0] = __builtin_amdgcn_cvt_pkrtz(a[0], a[1]);
  u.p[1] = __builtin_amdgcn_cvt_pkrtz(a[2], a[3]);
  u.p[2] = __builtin_amdgcn_cvt_pkrtz(b[0], b[1]);
  u.p[3] = __builtin_amdgcn_cvt_pkrtz(b[2], b[3]);
  return u.v;
}

// w1s[kk*8192 + col*32 + e] = W1[(kk*32+e)*256 + col]   (kk<4, col<256, e<32)
// w2s[kk*2048 + j*32 + e]   = W2[(kk*32+e)*64 + j]      (kk<8, j<64,  e<32)
__global__ __launch_bounds__(256) void prep_w(const float* __restrict__ W1,
                                              const float* __restrict__ W2,
                                              h16* __restrict__ w1s,
                                              h16* __restrict__ w2s) {
  int t = blockIdx.x * 256 + threadIdx.x;
  if (t < 128 * 256) {
    int row = t >> 8, col = t & 255;          // W1[row][col]
    int kk = row >> 5, e = row & 31;
    w1s[kk * 8192 + col * 32 + e] = (h16)W1[t];
  } else if (t < 128 * 256 + 256 * 64) {
    int t2 = t - 128 * 256;
    int row = t2 >> 6, j = t2 & 63;           // W2[row][j]
    int kk = row >> 5, e = row & 31;
    w2s[kk * 2048 + j * 32 + e] = (h16)W2[t2];
  }
}

// Runs LAST on the stream.
__global__ __launch_bounds__(256) void write_ss(const int* __restrict__ ssz,
                                                float* __restrict__ outp) {
  int b = blockIdx.x * 256 + threadIdx.x;
  if (b < 8192) outp[b] = (float)ssz[b];
}

// ================= Kernel A: MLP + Sinkhorn-init, store P0 (f32) =============
// LDS arena 32768 (5 blocks/CU): xh [64][128]swz -> hh [64][256]swz -> P0-transpose
template<bool WSF>
__global__ __launch_bounds__(256, 5) void mlp_init(
    const float* __restrict__ xf,
    const int* __restrict__ ssz,
    const float* __restrict__ gn,
    const float* __restrict__ b1,
    const float* __restrict__ b2,
    const h16* __restrict__ w1s,   // coalesced layout
    const h16* __restrict__ w2s,
    const float* __restrict__ W1f,
    const float* __restrict__ W2f,
    float* __restrict__ outp) {
  __shared__ __align__(16) char smem[32768];

  const int tid = threadIdx.x, b = blockIdx.x;
  const int w = tid >> 6, lane = tid & 63, g = lane >> 4, lc = lane & 15;
  const int k = ssz[b];
  const int sr = tid >> 2, sseg = tid & 3;

  {  // stage x -> f16 LDS xh [64][128] swizzled: byte = r*256 + c*2 ^ ((r&7)<<4)
    const float* src = xf + (size_t)b * 8192 + sr * 128 + sseg * 32;
#pragma unroll
    for (int v = 0; v < 4; ++v) {
      const int byte = (sr * 256 + (sseg * 32 + v * 8) * 2) ^ ((sr & 7) << 4);
      *(h8*)(smem + byte) =
          cvt8(*(const v4f*)(src + v * 8), *(const v4f*)(src + v * 8 + 4));
    }
  }
  float b1v[4], b2v[4];
#pragma unroll
  for (int n = 0; n < 4; ++n) b1v[n] = b1[w * 64 + n * 16 + lc];
#pragma unroll
  for (int n = 0; n < 4; ++n) b2v[n] = b2[n * 16 + lc];
  __syncthreads();

  // GEMM1: h = relu(x@W1+b1); wave w -> cols [64w,64w+64)
  v4f acc1[4][4];
#pragma unroll
  for (int m = 0; m < 4; ++m)
#pragma unroll
    for (int n = 0; n < 4; ++n) acc1[m][n] = (v4f){0.f, 0.f, 0.f, 0.f};
#pragma unroll
  for (int kk = 0; kk < 4; ++kk) {
    h8 av[4], bv[4];
#pragma unroll
    for (int m = 0; m < 4; ++m) {
      const int row = lc + 16 * m;
      const int byte = (row * 256 + (kk * 32 + 8 * g) * 2) ^ ((row & 7) << 4);
      av[m] = *(const h8*)(smem + byte);
    }
#pragma unroll
    for (int n = 0; n < 4; ++n) {
      if (WSF) {
        // 16 fully-used 64B lines per instruction (coalesced layout)
        bv[n] = *(const h8*)&w1s[kk * 8192 + (w * 64 + n * 16 + lc) * 32 + 8 * g];
      } else {
        h8 t;
#pragma unroll
        for (int e = 0; e < 8; ++e)
          t[e] = (h16)W1f[(kk * 32 + 8 * g + e) * 256 + (w * 64 + n * 16 + lc)];
        bv[n] = t;
      }
    }
#pragma unroll
    for (int m = 0; m < 4; ++m)
#pragma unroll
      for (int n = 0; n < 4; ++n)
        acc1[m][n] = __builtin_amdgcn_mfma_f32_16x16x32_f16(av[m], bv[n], acc1[m][n], 0, 0, 0);
  }

  // gn prefetch in LOW-pressure window; gated on wave-active
  float gnr[4][4];
  if (16 * w < k) {
    const float* gnb = gn + (size_t)b * 4096;
#pragma unroll
    for (int i = 0; i < 4; ++i)
#pragma unroll
      for (int n = 0; n < 4; ++n)
        gnr[i][n] = gnb[(16 * w + 4 * g + i) * 64 + 16 * n + lc];
  }

  __syncthreads();   // xh dead; arena becomes hh
  // hh store: byte = row*512 + col*2 ^ ((row&7)<<4)
#pragma unroll
  for (int m = 0; m < 4; ++m)
#pragma unroll
    for (int n = 0; n < 4; ++n)
#pragma unroll
      for (int q = 0; q < 4; ++q) {
        const int row = 16 * m + 4 * g + q;
        const int col = w * 64 + 16 * n + lc;
        const int byte = (row * 512 + col * 2) ^ ((row & 7) << 4);
        *(h16*)(smem + byte) = (h16)fmaxf(acc1[m][n][q] + b1v[n], 0.0f);
      }
  __syncthreads();

  // GEMM2: net rows [16w,16w+16); thread owns rows 16w+4g+i, cols 16n+lc
  v4f acc2[4];
#pragma unroll
  for (int n = 0; n < 4; ++n) acc2[n] = (v4f){0.f, 0.f, 0.f, 0.f};
  {
    const int row2 = 16 * w + lc;
#pragma unroll
    for (int kk = 0; kk < 8; ++kk) {
      const int byte = (row2 * 512 + (kk * 32 + 8 * g) * 2) ^ ((row2 & 7) << 4);
      h8 av = *(const h8*)(smem + byte);
#pragma unroll
      for (int n = 0; n < 4; ++n) {
        h8 bv;
        if (WSF) {
          bv = *(const h8*)&w2s[kk * 2048 + (n * 16 + lc) * 32 + 8 * g];
        } else {
          h8 t;
#pragma unroll
          for (int e = 0; e < 8; ++e)
            t[e] = (h16)W2f[(kk * 32 + 8 * g + e) * 64 + (n * 16 + lc)];
          bv = t;
        }
        acc2[n] = __builtin_amdgcn_mfma_f32_16x16x32_f16(av, bv, acc2[n], 0, 0, 0);
      }
    }
  }

  // init: P0 = exp2((la - rowmax)*10*log2e), masked -> 0
  float p[4][4];
#pragma unroll
  for (int i = 0; i < 4; ++i)
#pragma unroll
    for (int n = 0; n < 4; ++n) p[i][n] = 0.0f;
  if (16 * w < k) {
#pragma unroll
    for (int i = 0; i < 4; ++i) {
      const int row = 16 * w + 4 * g + i;
      float la[4];
#pragma unroll
      for (int n = 0; n < 4; ++n) {
        const int col = 16 * n + lc;
        const bool valid = (row < k) && (col < k);
        const float v = acc2[n][i] + b2v[n] + gnr[i][n];
        la[n] = valid ? v : -1e30f;
      }
      float m_ = fmaxf(fmaxf(la[0], la[1]), fmaxf(la[2], la[3]));
      m_ = red16_max(m_);
#pragma unroll
      for (int n = 0; n < 4; ++n)
        p[i][n] = (la[n] > -1e29f) ? exp2f((la[n] - m_) * 14.4269504089f) : 0.0f;
    }
  }

  // ---- P0 transpose to B-wave order via LDS (arena dead), then contiguous
  //      64B/thread global stores (R8-verified clean-write pattern).
  // B-flat: flat[((mj*4+nr)*64 + L)*4 + q] = P[16nr+(L&15)][16mj+4*(L>>4)+q]
  // Thread (w,g,lc) elem (i,n): idx = ((n*4+w)*64 + 16*(lc>>2) + 4g + i)*4 + (lc&3)
  // LDS pad: +4 dwords per 32 (keeps 16B alignment; <=2-way wr, 4-way rd).
  __syncthreads();   // hh dead (all GEMM2 reads complete)
  {
    float* lds = (float*)smem;
#pragma unroll
    for (int i = 0; i < 4; ++i)
#pragma unroll
      for (int n = 0; n < 4; ++n) {
        const int idx = ((n * 4 + w) * 64 + 16 * (lc >> 2) + 4 * g + i) * 4 + (lc & 3);
        lds[idx + 4 * (idx >> 5)] = p[i][n];
      }
  }
  __syncthreads();
  {
    const float* lds = (const float*)smem;
    float* P0 = outp + 8192 + (size_t)b * 8192;
#pragma unroll
    for (int j = 0; j < 4; ++j) {
      const int f = tid * 16 + j * 4;
      *(v4f*)&P0[f] = *(const v4f*)&lds[f + 4 * (f >> 5)];
    }
  }
}

// ================= Kernel B: wave-per-batch Sinkhorn + GEMM3, ZERO barriers ==
// Per-wave private 8KB pth: P^T subtiled [i>>3][j][i&7] f16 (conflict-free b128)
__global__ __launch_bounds__(256, 4) void sink_out(
    const float* __restrict__ xf,
    const int* __restrict__ ssz,
    float* __restrict__ outp) {
  __shared__ h16 pth_all[4][4096];

  const int tid = threadIdx.x;
  const int w = tid >> 6, lane = tid & 63, g = lane >> 4, lc = lane & 15;
  h16* pth = pth_all[w];

  const int b = blockIdx.x * 4 + w;
  const int k = ssz[b];
  const int mcnt = (k + 15) >> 4;
  const int kk3max = (k + 31) >> 5;
  const float* xb = xf + (size_t)b * 8192;

  // load P0: 16 coalesced v4f -> p[mj][nr][q] = P[16nr+lc][16mj+4g+q]
  v4f p[4][4];
  {
    const float* P0 = outp + 8192 + (size_t)b * 8192;
#pragma unroll
    for (int mj = 0; mj < 4; ++mj)
#pragma unroll
      for (int nr = 0; nr < 4; ++nr)
        p[mj][nr] = *(const v4f*)&P0[((mj * 4 + nr) * 64 + lane) * 4];
  }

  // 20 Sinkhorn iterations, fully in-register, zero barriers
#pragma unroll 1
  for (int it = 0; it < 20; ++it) {
#pragma unroll
    for (int nr = 0; nr < 4; ++nr)
      if (nr < mcnt) {
        float s = 0.0f;
#pragma unroll
        for (int mj = 0; mj < 4; ++mj)
          if (mj < mcnt)
            s += (p[mj][nr][0] + p[mj][nr][1]) + (p[mj][nr][2] + p[mj][nr][3]);
        s += __shfl_xor(s, 16);
        s += __shfl_xor(s, 32);
        const float sc = frcp(s + 1e-30f);
#pragma unroll
        for (int mj = 0; mj < 4; ++mj)
          if (mj < mcnt) {
            p[mj][nr][0] *= sc; p[mj][nr][1] *= sc;
            p[mj][nr][2] *= sc; p[mj][nr][3] *= sc;
          }
      }
#pragma unroll
    for (int mj = 0; mj < 4; ++mj)
      if (mj < mcnt) {
#pragma unroll
        for (int q = 0; q < 4; ++q) {
          float c = 0.0f;
#pragma unroll
          for (int nr = 0; nr < 4; ++nr)
            if (nr < mcnt) c += p[mj][nr][q];
          c = red16_sum(c);
          const float sc = frcp(c + 1e-30f);
#pragma unroll
          for (int nr = 0; nr < 4; ++nr)
            if (nr < mcnt) p[mj][nr][q] *= sc;
        }
      }
  }

  // stage P^T: pth[(i>>3)*512 + j*8 + (i&7)], i = 16nr+lc, j = 16mj+4g+q
#pragma unroll
  for (int mj = 0; mj < 4; ++mj)
#pragma unroll
    for (int nr = 0; nr < 4; ++nr)
#pragma unroll
      for (int q = 0; q < 4; ++q)
        pth[((2 * nr + (lc >> 3)) * 64 + 16 * mj + 4 * g + q) * 8 + (lc & 7)] =
            (h16)p[mj][nr][q];
  asm volatile("s_waitcnt lgkmcnt(0)" ::: "memory");

  float* outb = outp + 8192 + (size_t)b * 8192;
#pragma unroll 1
  for (int c = 0; c < 4; ++c) {  // f-chunks of 32
    v4f acc3[4][2];
#pragma unroll
    for (int m = 0; m < 4; ++m)
#pragma unroll
      for (int nn = 0; nn < 2; ++nn) acc3[m][nn] = (v4f){0.f, 0.f, 0.f, 0.f};
#pragma unroll 1
    for (int kk = 0; kk < kk3max; ++kk) {
      h8 ap[4];
#pragma unroll
      for (int m = 0; m < 4; ++m)
        if (m < mcnt)
          ap[m] = *(const h8*)&pth[((4 * kk + g) * 64 + 16 * m + lc) * 8];
#pragma unroll
      for (int nn = 0; nn < 2; ++nn) {
        const int f = 16 * (2 * c + nn) + lc;
        v4f x0, x1;
#pragma unroll
        for (int e = 0; e < 4; ++e) x0[e] = xb[(kk * 32 + 8 * g + e) * 128 + f];
#pragma unroll
        for (int e = 0; e < 4; ++e) x1[e] = xb[(kk * 32 + 8 * g + 4 + e) * 128 + f];
        h8 bxx = cvt8(x0, x1);
#pragma unroll
        for (int m = 0; m < 4; ++m)
          if (m < mcnt)
            acc3[m][nn] = __builtin_amdgcn_mfma_f32_16x16x32_f16(ap[m], bxx, acc3[m][nn], 0, 0, 0);
      }
    }
#pragma unroll
    for (int m = 0; m < 4; ++m)
#pragma unroll
      for (int nn = 0; nn < 2; ++nn)
#pragma unroll
        for (int q = 0; q < 4; ++q)
          outb[(16 * m + 4 * g + q) * 128 + 16 * (2 * c + nn) + lc] = acc3[m][nn][q];
  }
}

extern "C" void kernel_launch(void* const* d_in, const int* in_sizes, int n_in,
                              void* d_out, int out_size, void* d_ws, size_t ws_size,
                              hipStream_t stream) {
  const float* xf = (const float*)d_in[0];
  const int* ssz = (const int*)d_in[1];
  // d_in[2] = maskB: unused (recomputed from set_size)
  const float* gn = (const float*)d_in[3];
  const float* W1 = (const float*)d_in[4];
  const float* b1 = (const float*)d_in[5];
  const float* W2 = (const float*)d_in[6];
  const float* b2 = (const float*)d_in[7];
  float* outp = (float*)d_out;

  const size_t ws_need = (size_t)(128 * 256 + 256 * 64) * sizeof(h16);  // 98304 B
  const bool use_ws = (d_ws != nullptr) && (ws_size >= ws_need);

  if (use_ws) {
    h16* w1s = (h16*)d_ws;             // [4][256][32] f16
    h16* w2s = w1s + 128 * 256;        // [8][64][32]  f16
    prep_w<<<192, 256, 0, stream>>>(W1, W2, w1s, w2s);
    mlp_init<true><<<8192, 256, 0, stream>>>(xf, ssz, gn, b1, b2, w1s, w2s,
                                             W1, W2, outp);
  } else {
    mlp_init<false><<<8192, 256, 0, stream>>>(xf, ssz, gn, b1, b2,
                                              (const h16*)nullptr,
                                              (const h16*)nullptr,
                                              W1, W2, outp);
  }
  sink_out<<<2048, 256, 0, stream>>>(xf, ssz, outp);
  // set_size written LAST so nothing can clobber [0:8192).
  write_ss<<<32, 256, 0, stream>>>(ssz, outp);
}

// Round 13
// 352.078 us; speedup vs baseline: 2.3417x; 1.2625x over previous
//
#include <hip/hip_runtime.h>
#include <hip/hip_bf16.h>

// PermutationGenerator: B=8192, N=64, D=128, LATENT=256, TEMP=0.1, 20 Sinkhorn iters.
// d_in (ALL f32): [0] padded [B][64][128], [1] set_size int32 [B], [2] maskB (UNUSED),
//       [3] gumbel [B][64][64], [4] W1 [128][256], [5] b1 [256],
//       [6] W2 [256][64], [7] b2 [64]
// d_out f32: [0:8192] set_size, then permuted [B][64][128].
//
// R13: ONE change vs R12 — drop the min-waves launch bound on mlp_init.
// Evidence: launch_bounds(256,5) forced VGPR cap 48 < acc1's 64 => scratch
// spill since R10 (WRITE 452-499MB vs 131MB payload in unbounded R8). G6:
// the bound constrained the allocator harder than the occupancy it bought
// (R4/R10: occupancy never helped this kernel family anyway).
// Keeps R12's verified wins: coalesced weight staging (w1s/w2s, k-innermost),
// P0 store via LDS transpose -> 64B-contiguous stores, gated gn prefetch.
// B: R11 wave-per-batch zero-barrier Sinkhorn+GEMM3 (~5TB/s, at roofline).

typedef _Float16 h16;
typedef h16 h8 __attribute__((ext_vector_type(8)));
typedef __fp16 fp16x2 __attribute__((ext_vector_type(2)));
typedef float v4f __attribute__((ext_vector_type(4)));

template<int CTRL>
__device__ __forceinline__ float dppf(float x) {
  return __int_as_float(__builtin_amdgcn_update_dpp(
      0, __float_as_int(x), CTRL, 0xF, 0xF, true));
}
__device__ __forceinline__ float red16_sum(float x) {
  x += dppf<0xB1>(x);
  x += dppf<0x4E>(x);
  x += dppf<0x124>(x);
  x += dppf<0x128>(x);
  return x;
}
__device__ __forceinline__ float red16_max(float x) {
  x = fmaxf(x, dppf<0xB1>(x));
  x = fmaxf(x, dppf<0x4E>(x));
  x = fmaxf(x, dppf<0x124>(x));
  x = fmaxf(x, dppf<0x128>(x));
  return x;
}
__device__ __forceinline__ float frcp(float x) { return __builtin_amdgcn_rcpf(x); }
__device__ __forceinline__ h8 cvt8(v4f a, v4f b) {
  union { h8 v; fp16x2 p[4]; } u;
  u.p[0] = __builtin_amdgcn_cvt_pkrtz(a[0], a[1]);
  u.p[1] = __builtin_amdgcn_cvt_pkrtz(a[2], a[3]);
  u.p[2] = __builtin_amdgcn_cvt_pkrtz(b[0], b[1]);
  u.p[3] = __builtin_amdgcn_cvt_pkrtz(b[2], b[3]);
  return u.v;
}

// w1s[kk*8192 + col*32 + e] = W1[(kk*32+e)*256 + col]   (kk<4, col<256, e<32)
// w2s[kk*2048 + j*32 + e]   = W2[(kk*32+e)*64 + j]      (kk<8, j<64,  e<32)
__global__ __launch_bounds__(256) void prep_w(const float* __restrict__ W1,
                                              const float* __restrict__ W2,
                                              h16* __restrict__ w1s,
                                              h16* __restrict__ w2s) {
  int t = blockIdx.x * 256 + threadIdx.x;
  if (t < 128 * 256) {
    int row = t >> 8, col = t & 255;          // W1[row][col]
    int kk = row >> 5, e = row & 31;
    w1s[kk * 8192 + col * 32 + e] = (h16)W1[t];
  } else if (t < 128 * 256 + 256 * 64) {
    int t2 = t - 128 * 256;
    int row = t2 >> 6, j = t2 & 63;           // W2[row][j]
    int kk = row >> 5, e = row & 31;
    w2s[kk * 2048 + j * 32 + e] = (h16)W2[t2];
  }
}

// Runs LAST on the stream.
__global__ __launch_bounds__(256) void write_ss(const int* __restrict__ ssz,
                                                float* __restrict__ outp) {
  int b = blockIdx.x * 256 + threadIdx.x;
  if (b < 8192) outp[b] = (float)ssz[b];
}

// ================= Kernel A: MLP + Sinkhorn-init, store P0 (f32) =============
// LDS arena 32768: xh [64][128]swz -> hh [64][256]swz -> P0-transpose
template<bool WSF>
__global__ __launch_bounds__(256) void mlp_init(
    const float* __restrict__ xf,
    const int* __restrict__ ssz,
    const float* __restrict__ gn,
    const float* __restrict__ b1,
    const float* __restrict__ b2,
    const h16* __restrict__ w1s,   // coalesced layout
    const h16* __restrict__ w2s,
    const float* __restrict__ W1f,
    const float* __restrict__ W2f,
    float* __restrict__ outp) {
  __shared__ __align__(16) char smem[32768];

  const int tid = threadIdx.x, b = blockIdx.x;
  const int w = tid >> 6, lane = tid & 63, g = lane >> 4, lc = lane & 15;
  const int k = ssz[b];
  const int sr = tid >> 2, sseg = tid & 3;

  {  // stage x -> f16 LDS xh [64][128] swizzled: byte = r*256 + c*2 ^ ((r&7)<<4)
    const float* src = xf + (size_t)b * 8192 + sr * 128 + sseg * 32;
#pragma unroll
    for (int v = 0; v < 4; ++v) {
      const int byte = (sr * 256 + (sseg * 32 + v * 8) * 2) ^ ((sr & 7) << 4);
      *(h8*)(smem + byte) =
          cvt8(*(const v4f*)(src + v * 8), *(const v4f*)(src + v * 8 + 4));
    }
  }
  float b1v[4], b2v[4];
#pragma unroll
  for (int n = 0; n < 4; ++n) b1v[n] = b1[w * 64 + n * 16 + lc];
#pragma unroll
  for (int n = 0; n < 4; ++n) b2v[n] = b2[n * 16 + lc];
  __syncthreads();

  // GEMM1: h = relu(x@W1+b1); wave w -> cols [64w,64w+64)
  v4f acc1[4][4];
#pragma unroll
  for (int m = 0; m < 4; ++m)
#pragma unroll
    for (int n = 0; n < 4; ++n) acc1[m][n] = (v4f){0.f, 0.f, 0.f, 0.f};
#pragma unroll
  for (int kk = 0; kk < 4; ++kk) {
    h8 av[4], bv[4];
#pragma unroll
    for (int m = 0; m < 4; ++m) {
      const int row = lc + 16 * m;
      const int byte = (row * 256 + (kk * 32 + 8 * g) * 2) ^ ((row & 7) << 4);
      av[m] = *(const h8*)(smem + byte);
    }
#pragma unroll
    for (int n = 0; n < 4; ++n) {
      if (WSF) {
        // 16 fully-used 64B lines per instruction (coalesced layout)
        bv[n] = *(const h8*)&w1s[kk * 8192 + (w * 64 + n * 16 + lc) * 32 + 8 * g];
      } else {
        h8 t;
#pragma unroll
        for (int e = 0; e < 8; ++e)
          t[e] = (h16)W1f[(kk * 32 + 8 * g + e) * 256 + (w * 64 + n * 16 + lc)];
        bv[n] = t;
      }
    }
#pragma unroll
    for (int m = 0; m < 4; ++m)
#pragma unroll
      for (int n = 0; n < 4; ++n)
        acc1[m][n] = __builtin_amdgcn_mfma_f32_16x16x32_f16(av[m], bv[n], acc1[m][n], 0, 0, 0);
  }

  // gn prefetch in LOW-pressure window; gated on wave-active
  float gnr[4][4];
  if (16 * w < k) {
    const float* gnb = gn + (size_t)b * 4096;
#pragma unroll
    for (int i = 0; i < 4; ++i)
#pragma unroll
      for (int n = 0; n < 4; ++n)
        gnr[i][n] = gnb[(16 * w + 4 * g + i) * 64 + 16 * n + lc];
  }

  __syncthreads();   // xh dead; arena becomes hh
  // hh store: byte = row*512 + col*2 ^ ((row&7)<<4)
#pragma unroll
  for (int m = 0; m < 4; ++m)
#pragma unroll
    for (int n = 0; n < 4; ++n)
#pragma unroll
      for (int q = 0; q < 4; ++q) {
        const int row = 16 * m + 4 * g + q;
        const int col = w * 64 + 16 * n + lc;
        const int byte = (row * 512 + col * 2) ^ ((row & 7) << 4);
        *(h16*)(smem + byte) = (h16)fmaxf(acc1[m][n][q] + b1v[n], 0.0f);
      }
  __syncthreads();

  // GEMM2: net rows [16w,16w+16); thread owns rows 16w+4g+i, cols 16n+lc
  v4f acc2[4];
#pragma unroll
  for (int n = 0; n < 4; ++n) acc2[n] = (v4f){0.f, 0.f, 0.f, 0.f};
  {
    const int row2 = 16 * w + lc;
#pragma unroll
    for (int kk = 0; kk < 8; ++kk) {
      const int byte = (row2 * 512 + (kk * 32 + 8 * g) * 2) ^ ((row2 & 7) << 4);
      h8 av = *(const h8*)(smem + byte);
#pragma unroll
      for (int n = 0; n < 4; ++n) {
        h8 bv;
        if (WSF) {
          bv = *(const h8*)&w2s[kk * 2048 + (n * 16 + lc) * 32 + 8 * g];
        } else {
          h8 t;
#pragma unroll
          for (int e = 0; e < 8; ++e)
            t[e] = (h16)W2f[(kk * 32 + 8 * g + e) * 64 + (n * 16 + lc)];
          bv = t;
        }
        acc2[n] = __builtin_amdgcn_mfma_f32_16x16x32_f16(av, bv, acc2[n], 0, 0, 0);
      }
    }
  }

  // init: P0 = exp2((la - rowmax)*10*log2e), masked -> 0
  float p[4][4];
#pragma unroll
  for (int i = 0; i < 4; ++i)
#pragma unroll
    for (int n = 0; n < 4; ++n) p[i][n] = 0.0f;
  if (16 * w < k) {
#pragma unroll
    for (int i = 0; i < 4; ++i) {
      const int row = 16 * w + 4 * g + i;
      float la[4];
#pragma unroll
      for (int n = 0; n < 4; ++n) {
        const int col = 16 * n + lc;
        const bool valid = (row < k) && (col < k);
        const float v = acc2[n][i] + b2v[n] + gnr[i][n];
        la[n] = valid ? v : -1e30f;
      }
      float m_ = fmaxf(fmaxf(la[0], la[1]), fmaxf(la[2], la[3]));
      m_ = red16_max(m_);
#pragma unroll
      for (int n = 0; n < 4; ++n)
        p[i][n] = (la[n] > -1e29f) ? exp2f((la[n] - m_) * 14.4269504089f) : 0.0f;
    }
  }

  // ---- P0 transpose to B-wave order via LDS (arena dead), then contiguous
  //      64B/thread global stores.
  // B-flat: flat[((mj*4+nr)*64 + L)*4 + q] = P[16nr+(L&15)][16mj+4*(L>>4)+q]
  // Thread (w,g,lc) elem (i,n): idx = ((n*4+w)*64 + 16*(lc>>2) + 4g + i)*4 + (lc&3)
  // LDS pad: +4 dwords per 32 (16B-aligned v4f reads preserved).
  __syncthreads();   // hh dead (all GEMM2 reads complete)
  {
    float* lds = (float*)smem;
#pragma unroll
    for (int i = 0; i < 4; ++i)
#pragma unroll
      for (int n = 0; n < 4; ++n) {
        const int idx = ((n * 4 + w) * 64 + 16 * (lc >> 2) + 4 * g + i) * 4 + (lc & 3);
        lds[idx + 4 * (idx >> 5)] = p[i][n];
      }
  }
  __syncthreads();
  {
    const float* lds = (const float*)smem;
    float* P0 = outp + 8192 + (size_t)b * 8192;
#pragma unroll
    for (int j = 0; j < 4; ++j) {
      const int f = tid * 16 + j * 4;
      *(v4f*)&P0[f] = *(const v4f*)&lds[f + 4 * (f >> 5)];
    }
  }
}

// ================= Kernel B: wave-per-batch Sinkhorn + GEMM3, ZERO barriers ==
// Per-wave private 8KB pth: P^T subtiled [i>>3][j][i&7] f16 (conflict-free b128)
__global__ __launch_bounds__(256, 4) void sink_out(
    const float* __restrict__ xf,
    const int* __restrict__ ssz,
    float* __restrict__ outp) {
  __shared__ h16 pth_all[4][4096];

  const int tid = threadIdx.x;
  const int w = tid >> 6, lane = tid & 63, g = lane >> 4, lc = lane & 15;
  h16* pth = pth_all[w];

  const int b = blockIdx.x * 4 + w;
  const int k = ssz[b];
  const int mcnt = (k + 15) >> 4;
  const int kk3max = (k + 31) >> 5;
  const float* xb = xf + (size_t)b * 8192;

  // load P0: 16 coalesced v4f -> p[mj][nr][q] = P[16nr+lc][16mj+4g+q]
  v4f p[4][4];
  {
    const float* P0 = outp + 8192 + (size_t)b * 8192;
#pragma unroll
    for (int mj = 0; mj < 4; ++mj)
#pragma unroll
      for (int nr = 0; nr < 4; ++nr)
        p[mj][nr] = *(const v4f*)&P0[((mj * 4 + nr) * 64 + lane) * 4];
  }

  // 20 Sinkhorn iterations, fully in-register, zero barriers
#pragma unroll 1
  for (int it = 0; it < 20; ++it) {
#pragma unroll
    for (int nr = 0; nr < 4; ++nr)
      if (nr < mcnt) {
        float s = 0.0f;
#pragma unroll
        for (int mj = 0; mj < 4; ++mj)
          if (mj < mcnt)
            s += (p[mj][nr][0] + p[mj][nr][1]) + (p[mj][nr][2] + p[mj][nr][3]);
        s += __shfl_xor(s, 16);
        s += __shfl_xor(s, 32);
        const float sc = frcp(s + 1e-30f);
#pragma unroll
        for (int mj = 0; mj < 4; ++mj)
          if (mj < mcnt) {
            p[mj][nr][0] *= sc; p[mj][nr][1] *= sc;
            p[mj][nr][2] *= sc; p[mj][nr][3] *= sc;
          }
      }
#pragma unroll
    for (int mj = 0; mj < 4; ++mj)
      if (mj < mcnt) {
#pragma unroll
        for (int q = 0; q < 4; ++q) {
          float c = 0.0f;
#pragma unroll
          for (int nr = 0; nr < 4; ++nr)
            if (nr < mcnt) c += p[mj][nr][q];
          c = red16_sum(c);
          const float sc = frcp(c + 1e-30f);
#pragma unroll
          for (int nr = 0; nr < 4; ++nr)
            if (nr < mcnt) p[mj][nr][q] *= sc;
        }
      }
  }

  // stage P^T: pth[(i>>3)*512 + j*8 + (i&7)], i = 16nr+lc, j = 16mj+4g+q
#pragma unroll
  for (int mj = 0; mj < 4; ++mj)
#pragma unroll
    for (int nr = 0; nr < 4; ++nr)
#pragma unroll
      for (int q = 0; q < 4; ++q)
        pth[((2 * nr + (lc >> 3)) * 64 + 16 * mj + 4 * g + q) * 8 + (lc & 7)] =
            (h16)p[mj][nr][q];
  asm volatile("s_waitcnt lgkmcnt(0)" ::: "memory");

  float* outb = outp + 8192 + (size_t)b * 8192;
#pragma unroll 1
  for (int c = 0; c < 4; ++c) {  // f-chunks of 32
    v4f acc3[4][2];
#pragma unroll
    for (int m = 0; m < 4; ++m)
#pragma unroll
      for (int nn = 0; nn < 2; ++nn) acc3[m][nn] = (v4f){0.f, 0.f, 0.f, 0.f};
#pragma unroll 1
    for (int kk = 0; kk < kk3max; ++kk) {
      h8 ap[4];
#pragma unroll
      for (int m = 0; m < 4; ++m)
        if (m < mcnt)
          ap[m] = *(const h8*)&pth[((4 * kk + g) * 64 + 16 * m + lc) * 8];
#pragma unroll
      for (int nn = 0; nn < 2; ++nn) {
        const int f = 16 * (2 * c + nn) + lc;
        v4f x0, x1;
#pragma unroll
        for (int e = 0; e < 4; ++e) x0[e] = xb[(kk * 32 + 8 * g + e) * 128 + f];
#pragma unroll
        for (int e = 0; e < 4; ++e) x1[e] = xb[(kk * 32 + 8 * g + 4 + e) * 128 + f];
        h8 bxx = cvt8(x0, x1);
#pragma unroll
        for (int m = 0; m < 4; ++m)
          if (m < mcnt)
            acc3[m][nn] = __builtin_amdgcn_mfma_f32_16x16x32_f16(ap[m], bxx, acc3[m][nn], 0, 0, 0);
      }
    }
#pragma unroll
    for (int m = 0; m < 4; ++m)
#pragma unroll
      for (int nn = 0; nn < 2; ++nn)
#pragma unroll
        for (int q = 0; q < 4; ++q)
          outb[(16 * m + 4 * g + q) * 128 + 16 * (2 * c + nn) + lc] = acc3[m][nn][q];
  }
}

extern "C" void kernel_launch(void* const* d_in, const int* in_sizes, int n_in,
                              void* d_out, int out_size, void* d_ws, size_t ws_size,
                              hipStream_t stream) {
  const float* xf = (const float*)d_in[0];
  const int* ssz = (const int*)d_in[1];
  // d_in[2] = maskB: unused (recomputed from set_size)
  const float* gn = (const float*)d_in[3];
  const float* W1 = (const float*)d_in[4];
  const float* b1 = (const float*)d_in[5];
  const float* W2 = (const float*)d_in[6];
  const float* b2 = (const float*)d_in[7];
  float* outp = (float*)d_out;

  const size_t ws_need = (size_t)(128 * 256 + 256 * 64) * sizeof(h16);  // 98304 B
  const bool use_ws = (d_ws != nullptr) && (ws_size >= ws_need);

  if (use_ws) {
    h16* w1s = (h16*)d_ws;             // [4][256][32] f16
    h16* w2s = w1s + 128 * 256;        // [8][64][32]  f16
    prep_w<<<192, 256, 0, stream>>>(W1, W2, w1s, w2s);
    mlp_init<true><<<8192, 256, 0, stream>>>(xf, ssz, gn, b1, b2, w1s, w2s,
                                             W1, W2, outp);
  } else {
    mlp_init<false><<<8192, 256, 0, stream>>>(xf, ssz, gn, b1, b2,
                                              (const h16*)nullptr,
                                              (const h16*)nullptr,
                                              W1, W2, outp);
  }
  sink_out<<<2048, 256, 0, stream>>>(xf, ssz, outp);
  // set_size written LAST so nothing can clobber [0:8192).
  write_ss<<<32, 256, 0, stream>>>(ssz, outp);
}